// Round 1
// baseline (1325.367 us; speedup 1.0000x reference)
//
#include <hip/hip_runtime.h>

#define NB 65536L      // batch rows
#define NPAD 320       // padded output dim (300 -> 320)

typedef float  floatx4 __attribute__((ext_vector_type(4)));
typedef short  short8  __attribute__((ext_vector_type(8)));

__device__ inline short f2bf(float f) {
  unsigned u = __builtin_bit_cast(unsigned, f);
  u += 0x7FFFu + ((u >> 16) & 1u);           // RNE
  return (short)(u >> 16);
}
__device__ inline float bf2f(unsigned short u) {
  unsigned v = ((unsigned)u) << 16;
  return __builtin_bit_cast(float, v);
}

#define GLOAD_LDS16(gp, lp) \
  __builtin_amdgcn_global_load_lds((const __attribute__((address_space(1))) void*)(gp), \
                                   (__attribute__((address_space(3))) void*)(lp), 16, 0, 0)

// ---------------------------------------------------------------------------
// prep_transpose: Wt [768][300] fp32 -> WtT bf16 [320][768]; Wim -> WimT [320][2048]
// ---------------------------------------------------------------------------
__global__ void prep_transpose(const float* __restrict__ Wt, const float* __restrict__ Wim,
                               unsigned short* __restrict__ WtT, unsigned short* __restrict__ WimT)
{
  int tid = blockIdx.x * 256 + threadIdx.x;
  if (tid < 320*768) {
    int n = tid / 768, k = tid % 768;
    WtT[tid] = (n < 300) ? (unsigned short)f2bf(Wt[k*300 + n]) : (unsigned short)0;
  } else {
    int t = tid - 320*768;
    if (t < 320*2048) {
      int n = t / 2048, k = t % 2048;
      WimT[t] = (n < 300) ? (unsigned short)f2bf(Wim[k*300 + n]) : (unsigned short)0;
    }
  }
}

// ---------------------------------------------------------------------------
// prep_afrag: A'[n][k] = Wq~[n]·Wk~[k]  (rows 0..299 = W rows, row 300 = bias)
// written in MFMA-B fragment order: AF[mod][ki][nt][lane][j], bf16, zero padded.
// alpha = p'^T A' p' with p' = [p ; 1]  reproduces (Wq^T p+bq)·(Wk^T p+bk).
// ---------------------------------------------------------------------------
__device__ inline void af_write(unsigned short* AF, int mod, int n, int k, float v) {
  int ki = k >> 5, nt = n >> 4;
  int ln = (n & 15) | (((k >> 3) & 3) << 4);
  int j  = k & 7;
  AF[((((mod*10 + ki)*20 + nt) << 6) + ln)*8 + j] = (unsigned short)f2bf(v);
}

__global__ void prep_afrag(const float* WqT_, const float* bqT_, const float* WkT_, const float* bkT_,
                           const float* WqI_, const float* bqI_, const float* WkI_, const float* bkI_,
                           const float* WqC_, const float* bqC_, const float* WkC_, const float* bkC_,
                           unsigned short* __restrict__ AF)
{
  const int mod = blockIdx.z;
  const float* Wq = (mod==0) ? WqT_ : (mod==1) ? WqI_ : WqC_;
  const float* bq = (mod==0) ? bqT_ : (mod==1) ? bqI_ : bqC_;
  const float* Wk = (mod==0) ? WkT_ : (mod==1) ? WkI_ : WkC_;
  const float* bk = (mod==0) ? bkT_ : (mod==1) ? bkI_ : bkC_;
  const int n0 = blockIdx.x * 32, k0 = blockIdx.y * 32;
  const int tx = threadIdx.x, ty = threadIdx.y;
  const int t = ty*16 + tx;

  __shared__ float Qs[32][33], Ks[32][33];
  float a00=0.f, a01=0.f, a10=0.f, a11=0.f;

  for (int kk = 0; kk < 300; kk += 32) {
    __syncthreads();
    #pragma unroll
    for (int e = 0; e < 4; ++e) {
      int i = t + e*256; int r = i >> 5, c = i & 31;
      int gk = kk + c;
      float qv = 0.f, kv = 0.f;
      if (gk < 300) {
        int nr = n0 + r;
        if (nr < 300) qv = Wq[nr*300 + gk]; else if (nr == 300) qv = bq[gk];
        int kr = k0 + r;
        if (kr < 300) kv = Wk[kr*300 + gk]; else if (kr == 300) kv = bk[gk];
      }
      Qs[r][c] = qv; Ks[r][c] = kv;
    }
    __syncthreads();
    #pragma unroll
    for (int c = 0; c < 32; ++c) {
      float q0 = Qs[ty][c], q1 = Qs[ty+16][c];
      float v0 = Ks[tx][c], v1 = Ks[tx+16][c];
      a00 += q0*v0; a01 += q0*v1; a10 += q1*v0; a11 += q1*v1;
    }
  }
  af_write(AF, mod, n0+ty,    k0+tx,    a00);
  af_write(AF, mod, n0+ty,    k0+tx+16, a01);
  af_write(AF, mod, n0+ty+16, k0+tx,    a10);
  af_write(AF, mod, n0+ty+16, k0+tx+16, a11);
}

// ---------------------------------------------------------------------------
// gemm_proj: C[m][n] = sum_k X[m][k] * W[k][n] + bias[n]
//   X fp32 [65536][K], WT bf16 [320][K] (B^T layout), out fp32 or bf16.
//   Tile: BM=64, BN=320, BK=32. 4 waves in 2(m)x2(n); wave = 32 rows x 160 cols.
// ---------------------------------------------------------------------------
template<bool FP32OUT>
__global__ __launch_bounds__(256, 2)
void gemm_proj(const float* __restrict__ X, const unsigned short* __restrict__ WT,
               const float* __restrict__ bias, float* __restrict__ OF,
               unsigned short* __restrict__ OB, int K)
{
  const int tid  = threadIdx.x;
  const int lane = tid & 63;
  const int wave = tid >> 6;
  const int wm = wave >> 1, wn = wave & 1;
  const long m0 = (long)blockIdx.x * 64;

  __shared__ float          As[64*32];    // fp32 staging (cvt at frag read)
  __shared__ unsigned short Bs[320*32];   // bf16

  floatx4 acc[2][10];
  #pragma unroll
  for (int i = 0; i < 2; ++i)
    #pragma unroll
    for (int j = 0; j < 10; ++j) acc[i][j] = (floatx4){0.f,0.f,0.f,0.f};

  // precompute per-instruction staging pointers
  const float* gpa[2];
  const unsigned short* gpb[5];
  #pragma unroll
  for (int i2 = 0; i2 < 2; ++i2)
    gpa[i2] = X + (m0 + wave*16 + i2*8 + (lane>>3)) * K + (lane&7)*4;
  #pragma unroll
  for (int i2 = 0; i2 < 5; ++i2)
    gpb[i2] = WT + (long)(wave*80 + i2*16 + (lane>>2)) * K + (lane&3)*8;

  for (int kk = 0; kk < K; kk += 32) {
    __syncthreads();
    #pragma unroll
    for (int i2 = 0; i2 < 2; ++i2) {
      GLOAD_LDS16(gpa[i2], &As[(wave*2 + i2)*256]);
      gpa[i2] += 32;
    }
    #pragma unroll
    for (int i2 = 0; i2 < 5; ++i2) {
      GLOAD_LDS16(gpb[i2], &Bs[(wave*5 + i2)*512]);
      gpb[i2] += 32;
    }
    __syncthreads();

    short8 af[2];
    #pragma unroll
    for (int ms = 0; ms < 2; ++ms) {
      const float* p = &As[(wm*32 + ms*16 + (lane&15))*32 + (lane>>4)*8];
      floatx4 x0 = *(const floatx4*)p;
      floatx4 x1 = *(const floatx4*)(p + 4);
      short8 a;
      a[0]=f2bf(x0[0]); a[1]=f2bf(x0[1]); a[2]=f2bf(x0[2]); a[3]=f2bf(x0[3]);
      a[4]=f2bf(x1[0]); a[5]=f2bf(x1[1]); a[6]=f2bf(x1[2]); a[7]=f2bf(x1[3]);
      af[ms] = a;
    }
    #pragma unroll
    for (int nt = 0; nt < 10; ++nt) {
      const short8 bf = *(const short8*)&Bs[(wn*160 + nt*16 + (lane&15))*32 + (lane>>4)*8];
      acc[0][nt] = __builtin_amdgcn_mfma_f32_16x16x32_bf16(af[0], bf, acc[0][nt], 0, 0, 0);
      acc[1][nt] = __builtin_amdgcn_mfma_f32_16x16x32_bf16(af[1], bf, acc[1][nt], 0, 0, 0);
    }
  }

  const int q = lane >> 4, cl = lane & 15;
  #pragma unroll
  for (int ms = 0; ms < 2; ++ms) {
    const long mb = m0 + wm*32 + ms*16 + q*4;
    #pragma unroll
    for (int nt = 0; nt < 10; ++nt) {
      const int n = wn*160 + nt*16 + cl;
      if (n < 300) {
        const float bv = bias[n];
        #pragma unroll
        for (int r = 0; r < 4; ++r) {
          float v = acc[ms][nt][r] + bv;
          if (FP32OUT) OF[(mb + r)*300 + n] = v;
          else         OB[(mb + r)*300 + n] = (unsigned short)f2bf(v);
        }
      }
    }
  }
}

// ---------------------------------------------------------------------------
// branch_kernel: per 32-row tile: stage P_T/P_IM/P_CD (bf16, +1-augmented col),
// alpha_mod = p'^T A' p' via MFMA + rowdot, sigmoid/softmax, scaled stores.
// ---------------------------------------------------------------------------
__global__ __launch_bounds__(256, 2)
void branch_kernel(const float* __restrict__ PT, const unsigned short* __restrict__ PIM,
                   const unsigned short* __restrict__ PCD, const unsigned short* __restrict__ AF,
                   float* __restrict__ out1, float* __restrict__ out2)
{
  const int tid  = threadIdx.x;
  const int lane = tid & 63;
  const int wave = tid >> 6;
  const int wm = wave >> 1, wn = wave & 1;
  const long m0 = (long)blockIdx.x * 32;

  __shared__ unsigned short P[3][32*328];   // row stride 328 for bank spread
  __shared__ float alphaS[3][32];
  __shared__ float afS[2][32];

  if (tid < 96) alphaS[tid/32][tid%32] = 0.f;

  // stage P_T (fp32 -> bf16)
  for (int idx = tid; idx < 32*75; idx += 256) {
    int r = idx/75, c4 = idx - r*75;
    float4 v = *((const float4*)(PT + (m0 + r)*300) + c4);
    ushort4 w;
    w.x = (unsigned short)f2bf(v.x); w.y = (unsigned short)f2bf(v.y);
    w.z = (unsigned short)f2bf(v.z); w.w = (unsigned short)f2bf(v.w);
    *(ushort4*)&P[0][r*328 + c4*4] = w;
  }
  // stage P_IM, P_CD (bf16 passthrough)
  for (int idx = tid; idx < 32*75; idx += 256) {
    int r = idx/75, c4 = idx - r*75;
    *(ushort4*)&P[1][r*328 + c4*4] = *(const ushort4*)(PIM + (m0 + r)*300 + c4*4);
    *(ushort4*)&P[2][r*328 + c4*4] = *(const ushort4*)(PCD + (m0 + r)*300 + c4*4);
  }
  // augmented col 300 = 1.0, cols 301..327 = 0
  for (int idx = tid; idx < 32*28; idx += 256) {
    int r = idx/28, c = 300 + (idx - r*28);
    unsigned short val = (c == 300) ? (unsigned short)0x3F80 : (unsigned short)0;
    P[0][r*328 + c] = val; P[1][r*328 + c] = val; P[2][r*328 + c] = val;
  }
  __syncthreads();

  const int q = lane >> 4, cl = lane & 15;
  for (int mod = 0; mod < 3; ++mod) {
    floatx4 acc[10];
    #pragma unroll
    for (int i = 0; i < 10; ++i) acc[i] = (floatx4){0.f,0.f,0.f,0.f};
    const unsigned short* AFm = AF + mod*(10*20*64*8);

    for (int ki = 0; ki < 10; ++ki) {
      const short8 pf = *(const short8*)&P[mod][(wm*16 + cl)*328 + ki*32 + q*8];
      const unsigned short* fb = AFm + ((ki*20 + wn*10)*64 + lane)*8;
      #pragma unroll
      for (int nt = 0; nt < 10; ++nt) {
        const short8 bf = *(const short8*)(fb + nt*64*8);
        acc[nt] = __builtin_amdgcn_mfma_f32_16x16x32_bf16(pf, bf, acc[nt], 0, 0, 0);
      }
    }
    // rowdot: alpha[m] += sum_n P'[m][n] * S[m][n]
    float part[4] = {0.f, 0.f, 0.f, 0.f};
    for (int nt = 0; nt < 10; ++nt) {
      const int n = wn*160 + nt*16 + cl;
      #pragma unroll
      for (int r = 0; r < 4; ++r)
        part[r] += bf2f(P[mod][(wm*16 + q*4 + r)*328 + n]) * acc[nt][r];
    }
    #pragma unroll
    for (int m = 1; m < 16; m <<= 1) {
      #pragma unroll
      for (int r = 0; r < 4; ++r) part[r] += __shfl_xor(part[r], m, 64);
    }
    if (cl == 0) {
      #pragma unroll
      for (int r = 0; r < 4; ++r)
        atomicAdd(&alphaS[mod][wm*16 + q*4 + r], part[r]);
    }
  }
  __syncthreads();

  if (tid < 32) {
    const float inv = 0.057735026919f;  // 1/sqrt(300)
    float aT = alphaS[0][tid]*inv, aI = alphaS[1][tid]*inv, aC = alphaS[2][tid]*inv;
    float ZT = 1.f/(1.f + __expf(-aT));
    float ZI = 1.f/(1.f + __expf(-aI));
    float ZC = 1.f/(1.f + __expf(-aC));
    float M1 = ZI*ZT, M2 = ZC*ZT;
    float mx = fmaxf(M1, M2);
    float e1 = __expf(M1 - mx), e2 = __expf(M2 - mx);
    float s = e1 + e2;
    afS[0][tid] = e1/s; afS[1][tid] = e2/s;
  }
  __syncthreads();

  for (int idx = tid; idx < 32*75; idx += 256) {
    int r = idx/75, c4 = idx - r*75;
    float a1 = afS[0][r], a2 = afS[1][r];
    ushort4 wi = *(const ushort4*)&P[1][r*328 + c4*4];
    ushort4 wc = *(const ushort4*)&P[2][r*328 + c4*4];
    float4 o1, o2;
    o1.x = a1*bf2f(wi.x); o1.y = a1*bf2f(wi.y); o1.z = a1*bf2f(wi.z); o1.w = a1*bf2f(wi.w);
    o2.x = a2*bf2f(wc.x); o2.y = a2*bf2f(wc.y); o2.z = a2*bf2f(wc.z); o2.w = a2*bf2f(wc.w);
    *((float4*)(out1 + (m0 + r)*300) + c4) = o1;
    *((float4*)(out2 + (m0 + r)*300) + c4) = o2;
  }
}

// ---------------------------------------------------------------------------
extern "C" void kernel_launch(void* const* d_in, const int* in_sizes, int n_in,
                              void* d_out, int out_size, void* d_ws, size_t ws_size,
                              hipStream_t stream)
{
  const float* Tf  = (const float*)d_in[0];
  const float* IMf = (const float*)d_in[1];
  const float* CDf = (const float*)d_in[2];
  const float* Wt  = (const float*)d_in[3];
  const float* bt  = (const float*)d_in[4];
  const float* Wim = (const float*)d_in[5];
  const float* bim = (const float*)d_in[6];
  const float* WqT = (const float*)d_in[7];
  const float* bqT = (const float*)d_in[8];
  const float* WkT = (const float*)d_in[9];
  const float* bkT = (const float*)d_in[10];
  const float* WqI = (const float*)d_in[11];
  const float* bqI = (const float*)d_in[12];
  const float* WkI = (const float*)d_in[13];
  const float* bkI = (const float*)d_in[14];
  const float* WqC = (const float*)d_in[15];
  const float* bqC = (const float*)d_in[16];
  const float* WkC = (const float*)d_in[17];
  const float* bkC = (const float*)d_in[18];

  unsigned short* WtT  = (unsigned short*)d_ws;           // 320*768
  unsigned short* WimT = WtT + 320*768;                   // 320*2048
  unsigned short* AFr  = WimT + 320*2048;                 // 3*10*20*64*8 = 307200
  unsigned short* PIM  = AFr + 3*102400;                  // 65536*300 bf16
  unsigned short* PCD  = PIM + NB*300;

  float* out0 = (float*)d_out;
  float* out1 = out0 + NB*300;
  float* out2 = out1 + NB*300;

  hipLaunchKernelGGL(prep_transpose, dim3(3520), dim3(256), 0, stream, Wt, Wim, WtT, WimT);
  hipLaunchKernelGGL(prep_afrag, dim3(10,10,3), dim3(16,16), 0, stream,
                     WqT,bqT,WkT,bkT, WqI,bqI,WkI,bkI, WqC,bqC,WkC,bkC, AFr);
  hipLaunchKernelGGL((gemm_proj<true>),  dim3(1024), dim3(256), 0, stream,
                     Tf,  WtT,  bt,  out0, (unsigned short*)nullptr, 768);
  hipLaunchKernelGGL((gemm_proj<false>), dim3(1024), dim3(256), 0, stream,
                     IMf, WimT, bim, (float*)nullptr, PIM, 2048);
  hipLaunchKernelGGL((gemm_proj<false>), dim3(1024), dim3(256), 0, stream,
                     CDf, WtT,  bt,  (float*)nullptr, PCD, 768);
  hipLaunchKernelGGL(branch_kernel, dim3(2048), dim3(256), 0, stream,
                     out0, PIM, PCD, AFr, out1, out2);
}